// Round 1
// baseline (5030.404 us; speedup 1.0000x reference)
//
#include <hip/hip_runtime.h>

// Problem constants (fixed by reference)
#define K3c   27
#define Mc    100000
#define NINc  200000
#define NOUTc 400000
#define Cc    128
#define EPSc  1e-5f

#define PAIRS  32
#define CHUNKS (Mc / PAIRS)   // 3125 exactly

// ---------------------------------------------------------------------------
// Kernel 1: zero the output accumulator (51.2M floats) and the stats buffer
// ---------------------------------------------------------------------------
__global__ __launch_bounds__(256) void zero_kernel(float4* __restrict__ out4,
                                                   float4* __restrict__ stats4) {
    const int n4 = NOUTc * (Cc / 4);              // 12.8M float4
    const int stride = gridDim.x * blockDim.x;
    int idx = blockIdx.x * blockDim.x + threadIdx.x;
    const float4 z = make_float4(0.f, 0.f, 0.f, 0.f);
    for (int i = idx; i < n4; i += stride) out4[i] = z;
    if (idx < 128) stats4[idx] = z;               // 512 floats: sum/ssq/scale/shift
}

// ---------------------------------------------------------------------------
// Kernel 2: gather -> tile-GEMM -> atomic scatter-add
// Block: 256 threads, handles one (k, 32-pair chunk).
// LDS: feats tile 32x128 f32 (16KB) + W half-tile 64x128 f32 (32KB) = 48KB.
// Thread tile: 4 pairs x 4 cols (float4 accumulators).
// ---------------------------------------------------------------------------
__global__ __launch_bounds__(256, 2) void scatter_kernel(
    const float* __restrict__ feats, const float* __restrict__ W,
    const int* __restrict__ in_maps, const int* __restrict__ out_maps,
    float* __restrict__ out)
{
    __shared__ float Ws[64 * Cc];        // 32KB: half of W[k]
    __shared__ float fs[PAIRS * Cc];     // 16KB: gathered feats rows

    const int t    = threadIdx.x;
    const int bx   = blockIdx.x;
    const int k    = bx / CHUNKS;
    const int base = (bx % CHUNKS) * PAIRS;

    // --- gather 32 feats rows into LDS (coalesced float4) ---
    const float4* __restrict__ feats4 = (const float4*)feats;
    float4* fs4 = (float4*)fs;
    const int mapbase = k * Mc + base;
#pragma unroll
    for (int j = 0; j < 4; ++j) {
        int idx = t + j * 256;           // 0..1023
        int r = idx >> 5, c = idx & 31;
        int grow = in_maps[mapbase + r];
        fs4[idx] = feats4[grow * 32 + c];
    }

    const int tx = t & 31;               // col group (4 cols)
    const int ty = t >> 5;               // pair group (4 pairs)

    float4 acc[4];
#pragma unroll
    for (int p = 0; p < 4; ++p) acc[p] = make_float4(0.f, 0.f, 0.f, 0.f);

    float4* Ws4 = (float4*)Ws;

    // --- K loop in two halves of 64 (keeps LDS <= 48KB) ---
    for (int h = 0; h < 2; ++h) {
        __syncthreads();                 // fs ready (h=0) / previous half done (h=1)
        const float4* __restrict__ Wh4 = (const float4*)(W + k * Cc * Cc + h * 64 * Cc);
#pragma unroll
        for (int j = 0; j < 8; ++j) Ws4[t + j * 256] = Wh4[t + j * 256];
        __syncthreads();

        const float* fbase = fs + (ty * 4) * Cc + h * 64;
#pragma unroll 2
        for (int i = 0; i < 64; ++i) {
            float4 wv = Ws4[i * 32 + tx];
#pragma unroll
            for (int p = 0; p < 4; ++p) {
                float fv = fbase[p * Cc + i];
                acc[p].x = fmaf(fv, wv.x, acc[p].x);
                acc[p].y = fmaf(fv, wv.y, acc[p].y);
                acc[p].z = fmaf(fv, wv.z, acc[p].z);
                acc[p].w = fmaf(fv, wv.w, acc[p].w);
            }
        }
    }

    // --- scatter-add: 4 rows x 4 cols per thread ---
#pragma unroll
    for (int p = 0; p < 4; ++p) {
        int om = out_maps[mapbase + ty * 4 + p];
        float* dst = out + om * Cc + tx * 4;
        unsafeAtomicAdd(dst + 0, acc[p].x);
        unsafeAtomicAdd(dst + 1, acc[p].y);
        unsafeAtomicAdd(dst + 2, acc[p].z);
        unsafeAtomicAdd(dst + 3, acc[p].w);
    }
}

// ---------------------------------------------------------------------------
// Kernel 3: per-channel sum and sum-of-squares over 400000 rows
// Grid 1000 blocks x 256 threads; block handles 400 rows (8 rows/iter, 50 iters)
// ---------------------------------------------------------------------------
__global__ __launch_bounds__(256) void stats_kernel(const float4* __restrict__ out4,
                                                    float* __restrict__ stats) {
    const int t  = threadIdx.x;
    const int tx = t & 31;               // channel group: channels tx*4..tx*4+3
    const int ty = t >> 5;               // row offset 0..7

    float4 s = make_float4(0.f, 0.f, 0.f, 0.f);
    float4 q = make_float4(0.f, 0.f, 0.f, 0.f);
    int row0 = blockIdx.x * 400 + ty;
    for (int j = 0; j < 50; ++j) {
        float4 v = out4[(row0 + j * 8) * 32 + tx];
        s.x += v.x; s.y += v.y; s.z += v.z; s.w += v.w;
        q.x += v.x * v.x; q.y += v.y * v.y; q.z += v.z * v.z; q.w += v.w * v.w;
    }

    __shared__ float4 redS[256];
    __shared__ float4 redQ[256];
    redS[t] = s; redQ[t] = q;
    __syncthreads();
    if (ty == 0) {
#pragma unroll
        for (int jj = 1; jj < 8; ++jj) {
            float4 o = redS[jj * 32 + tx];
            s.x += o.x; s.y += o.y; s.z += o.z; s.w += o.w;
            float4 oq = redQ[jj * 32 + tx];
            q.x += oq.x; q.y += oq.y; q.z += oq.z; q.w += oq.w;
        }
        unsafeAtomicAdd(&stats[tx * 4 + 0], s.x);
        unsafeAtomicAdd(&stats[tx * 4 + 1], s.y);
        unsafeAtomicAdd(&stats[tx * 4 + 2], s.z);
        unsafeAtomicAdd(&stats[tx * 4 + 3], s.w);
        unsafeAtomicAdd(&stats[Cc + tx * 4 + 0], q.x);
        unsafeAtomicAdd(&stats[Cc + tx * 4 + 1], q.y);
        unsafeAtomicAdd(&stats[Cc + tx * 4 + 2], q.z);
        unsafeAtomicAdd(&stats[Cc + tx * 4 + 3], q.w);
    }
}

// ---------------------------------------------------------------------------
// Kernel 4: finalize BN scale/shift per channel
// ---------------------------------------------------------------------------
__global__ void finalize_kernel(const float* __restrict__ gamma,
                                const float* __restrict__ beta,
                                float* __restrict__ stats) {
    int c = threadIdx.x;
    float inv_n = 1.0f / (float)NOUTc;
    float mean = stats[c] * inv_n;
    float var  = stats[Cc + c] * inv_n - mean * mean;
    float scale = gamma[c] * rsqrtf(var + EPSc);
    stats[2 * Cc + c] = scale;
    stats[3 * Cc + c] = beta[c] - mean * scale;
}

// ---------------------------------------------------------------------------
// Kernel 5: in-place normalize  y = out*scale[c] + shift[c]
// ---------------------------------------------------------------------------
__global__ __launch_bounds__(256) void norm_kernel(float4* __restrict__ out4,
                                                   const float* __restrict__ stats) {
    const float4* stats4 = (const float4*)stats;
    int idx0 = blockIdx.x * blockDim.x + threadIdx.x;
    int c4 = idx0 & 31;                  // stride is a multiple of 32 -> invariant
    float4 sc = stats4[64 + c4];
    float4 sh = stats4[96 + c4];
    const int n4 = NOUTc * (Cc / 4);
    const int stride = gridDim.x * blockDim.x;
    for (int i = idx0; i < n4; i += stride) {
        float4 v = out4[i];
        v.x = v.x * sc.x + sh.x;
        v.y = v.y * sc.y + sh.y;
        v.z = v.z * sc.z + sh.z;
        v.w = v.w * sc.w + sh.w;
        out4[i] = v;
    }
}

// ---------------------------------------------------------------------------
extern "C" void kernel_launch(void* const* d_in, const int* in_sizes, int n_in,
                              void* d_out, int out_size, void* d_ws, size_t ws_size,
                              hipStream_t stream) {
    const float* feats    = (const float*)d_in[0];
    const float* W        = (const float*)d_in[1];
    const float* gamma    = (const float*)d_in[2];
    const float* beta     = (const float*)d_in[3];
    const int*   in_maps  = (const int*)d_in[4];
    const int*   out_maps = (const int*)d_in[5];
    float* out   = (float*)d_out;
    float* stats = (float*)d_ws;         // 512 floats: sum | ssq | scale | shift

    zero_kernel<<<4096, 256, 0, stream>>>((float4*)out, (float4*)stats);
    scatter_kernel<<<K3c * CHUNKS, 256, 0, stream>>>(feats, W, in_maps, out_maps, out);
    stats_kernel<<<1000, 256, 0, stream>>>((const float4*)out, stats);
    finalize_kernel<<<1, 128, 0, stream>>>(gamma, beta, stats);
    norm_kernel<<<4096, 256, 0, stream>>>((float4*)out, stats);
}

// Round 2
// 2328.182 us; speedup vs baseline: 2.1607x; 2.1607x over previous
//
#include <hip/hip_runtime.h>

// Problem constants (fixed by reference)
#define K3c    27
#define Mc     100000
#define NINc   200000
#define NOUTc  400000
#define Cc     128
#define EPSc   1e-5f

#define NBUCK  6250          // NOUTc >> 6 buckets per k
#define NCNT   (K3c * NBUCK) // 168,750 counters
#define BPK    391           // hist/build blocks per k (391*256 >= 100000)
#define CPK    1563          // gemm chunks of 64 pairs per k (1563*64 >= 100000)

// ws layout (byte offsets)
#define WS_STATS   0u          // 512 floats: sum | ssq | scale | shift
#define WS_COUNTS  4096u       // NCNT u32
#define WS_SIM     1048576u    // 2.7M int  sorted_im
#define WS_SOM     12582912u   // 2.7M int  sorted_om
#define WS_WFH     25165824u   // 27*2048 lanes * 8 shorts  (884,736 B)
#define WS_WFL     26214400u   // same

typedef __attribute__((ext_vector_type(8))) short short8;
typedef __attribute__((ext_vector_type(4))) float f32x4;

__device__ inline unsigned fbits(float f) { return __builtin_bit_cast(unsigned, f); }
__device__ inline float bfloat(unsigned u) { return __builtin_bit_cast(float, u); }

// pack truncated-bf16 of (f0,f1) into one u32 (f0 -> low16, f1 -> high16)
__device__ inline unsigned pack_hi2(float f0, float f1) {
    return (fbits(f0) >> 16) | (fbits(f1) & 0xFFFF0000u);
}
__device__ inline float trunc_bf16_f(float f) { return bfloat(fbits(f) & 0xFFFF0000u); }

__device__ inline unsigned short bf16_rne(float f) {
    unsigned u = fbits(f);
    u += 0x7FFFu + ((u >> 16) & 1u);
    return (unsigned short)(u >> 16);
}

// ---------------------------------------------------------------------------
// Kernel 1: zero output accumulator + stats + bucket counters
// ---------------------------------------------------------------------------
__global__ __launch_bounds__(256) void zero_kernel(float4* __restrict__ out4,
                                                   float* __restrict__ ws_stats,
                                                   unsigned* __restrict__ counts) {
    const int n4 = NOUTc * (Cc / 4);
    const int stride = gridDim.x * blockDim.x;
    int idx = blockIdx.x * blockDim.x + threadIdx.x;
    const float4 z = make_float4(0.f, 0.f, 0.f, 0.f);
    for (int i = idx; i < n4; i += stride) out4[i] = z;
    for (int i = idx; i < NCNT; i += stride) counts[i] = 0u;
    if (idx < 512) ws_stats[idx] = 0.f;
}

// ---------------------------------------------------------------------------
// Kernel 2: W -> per-lane MFMA B-fragment layout, RNE hi/lo bf16 split
// 27*4*8*64 = 55,296 lane-slots; one thread each; 8 elems per slot.
// B layout for 16x16x32: lane holds B[kk = kstep*32 + (lane>>4)*8 + j][n = cb*16 + (lane&15)]
// ---------------------------------------------------------------------------
__global__ __launch_bounds__(256) void wprep_kernel(const float* __restrict__ W,
                                                    short8* __restrict__ wfh,
                                                    short8* __restrict__ wfl) {
    int tid = blockIdx.x * 256 + threadIdx.x;     // grid = 216 blocks exactly
    int k     = tid >> 11;
    int rem   = tid & 2047;
    int kstep = rem >> 9;
    int cb    = (rem >> 6) & 7;
    int lane  = rem & 63;
    int n   = cb * 16 + (lane & 15);
    int kk0 = kstep * 32 + (lane >> 4) * 8;
    const float* src = W + k * (Cc * Cc) + kk0 * Cc + n;
    short8 h, l;
#pragma unroll
    for (int j = 0; j < 8; ++j) {
        float f = src[j * Cc];
        unsigned short hb = bf16_rne(f);
        h[j] = (short)hb;
        float hf = bfloat(((unsigned)hb) << 16);
        l[j] = (short)bf16_rne(f - hf);
    }
    wfh[tid] = h;
    wfl[tid] = l;
}

// ---------------------------------------------------------------------------
// Kernel 3: histogram of out rows into 64-row buckets, per k
// ---------------------------------------------------------------------------
__global__ __launch_bounds__(256) void hist_kernel(const int* __restrict__ out_maps,
                                                   unsigned* __restrict__ counts) {
    int b = blockIdx.x;
    int k = b / BPK;
    int m = (b - k * BPK) * 256 + threadIdx.x;
    if (m < Mc) {
        int om = out_maps[k * Mc + m];
        atomicAdd(&counts[k * NBUCK + (om >> 6)], 1u);
    }
}

// ---------------------------------------------------------------------------
// Kernel 4: single-block exclusive scan over all 168,750 counters (in place).
// Each k sums to exactly 100,000 -> global scan gives per-k base k*100000 free.
// ---------------------------------------------------------------------------
__global__ __launch_bounds__(1024) void scan_kernel(unsigned* __restrict__ counts) {
    __shared__ unsigned lds[1024];
    const int t = threadIdx.x;
    const int CHUNK = 165;                         // 1024*165 >= NCNT
    int base = t * CHUNK;
    unsigned s = 0;
    for (int j = 0; j < CHUNK; ++j) {
        int i = base + j;
        if (i < NCNT) s += counts[i];
    }
    lds[t] = s;
    __syncthreads();
    for (int off = 1; off < 1024; off <<= 1) {
        unsigned v = (t >= off) ? lds[t - off] : 0u;
        __syncthreads();
        lds[t] += v;
        __syncthreads();
    }
    unsigned run = lds[t] - s;                     // exclusive carry
    for (int j = 0; j < CHUNK; ++j) {
        int i = base + j;
        if (i < NCNT) {
            unsigned c = counts[i];
            counts[i] = run;
            run += c;
        }
    }
}

// ---------------------------------------------------------------------------
// Kernel 5: scatter pairs into bucket-sorted order (destroys offsets)
// ---------------------------------------------------------------------------
__global__ __launch_bounds__(256) void build_kernel(const int* __restrict__ in_maps,
                                                    const int* __restrict__ out_maps,
                                                    unsigned* __restrict__ offs,
                                                    int* __restrict__ sorted_im,
                                                    int* __restrict__ sorted_om) {
    int b = blockIdx.x;
    int k = b / BPK;
    int m = (b - k * BPK) * 256 + threadIdx.x;
    if (m < Mc) {
        int om = out_maps[k * Mc + m];
        int im = in_maps[k * Mc + m];
        unsigned pos = atomicAdd(&offs[k * NBUCK + (om >> 6)], 1u);
        sorted_im[pos] = im;
        sorted_om[pos] = om;
    }
}

// ---------------------------------------------------------------------------
// Kernel 6: gathered split-bf16 MFMA GEMM + bucket-local atomic scatter
// Block: 256 thr = 4 waves; tile = 64 sorted pairs x 128 cols, K=128.
// LDS: A hi/lo bf16 [64][136] (pad 8 -> uniform-bank ds_read_b128). 34.8 KB.
// Wave w handles rows w*16..w*16+15; 8 colblocks x 4 ksteps x 3 mfma = 96 MFMA.
// ---------------------------------------------------------------------------
__global__ __launch_bounds__(256) void gemm_scatter_kernel(
    const float* __restrict__ feats,
    const short8* __restrict__ wfh, const short8* __restrict__ wfl,
    const int* __restrict__ sorted_im, const int* __restrict__ sorted_om,
    float* __restrict__ out)
{
    __shared__ short fsh[64 * 136];
    __shared__ short fsl[64 * 136];

    const int t = threadIdx.x;
    const int bx = blockIdx.x;
    const int k = bx / CPK;
    const int c = bx - k * CPK;
    const int pairbase = k * Mc + c * 64;
    const int valid = min(64, Mc - c * 64);        // 64, or 32 on the last chunk

    // --- gather 64 feats rows, trunc-split fp32 -> bf16 hi/lo into LDS ---
    {
        const int r = t >> 2;                      // 0..63
        const int cg = t & 3;                      // col group of 32
        const bool ok = (r < valid);
        long im = ok ? (long)sorted_im[pairbase + r] : 0;
        const float4* src4 = (const float4*)(feats + im * Cc + cg * 32);
        unsigned* fh32 = (unsigned*)fsh;
        unsigned* fl32 = (unsigned*)fsl;
#pragma unroll
        for (int j = 0; j < 8; ++j) {
            float4 v = ok ? src4[j] : make_float4(0.f, 0.f, 0.f, 0.f);
            int col = cg * 32 + j * 4;
            int idx = r * 68 + (col >> 1);
            fh32[idx]     = pack_hi2(v.x, v.y);
            fh32[idx + 1] = pack_hi2(v.z, v.w);
            float lx = v.x - trunc_bf16_f(v.x);
            float ly = v.y - trunc_bf16_f(v.y);
            float lz = v.z - trunc_bf16_f(v.z);
            float lw = v.w - trunc_bf16_f(v.w);
            fl32[idx]     = pack_hi2(lx, ly);
            fl32[idx + 1] = pack_hi2(lz, lw);
        }
    }
    __syncthreads();

    const int wave = t >> 6;
    const int lane = t & 63;
    const int m    = lane & 15;
    const int quad = lane >> 4;

    f32x4 acc[8];
#pragma unroll
    for (int cb = 0; cb < 8; ++cb) acc[cb] = (f32x4){0.f, 0.f, 0.f, 0.f};

    const int arow = wave * 16 + m;
    for (int kstep = 0; kstep < 4; ++kstep) {
        const short* ah = fsh + arow * 136 + kstep * 32 + quad * 8;
        const short* al = fsl + arow * 136 + kstep * 32 + quad * 8;
        short8 a_hi = *(const short8*)ah;
        short8 a_lo = *(const short8*)al;
        int fb = ((k * 4 + kstep) * 8) * 64 + lane;
#pragma unroll
        for (int cb = 0; cb < 8; ++cb) {
            short8 b_hi = wfh[fb + cb * 64];
            short8 b_lo = wfl[fb + cb * 64];
            acc[cb] = __builtin_amdgcn_mfma_f32_16x16x32_bf16(a_hi, b_hi, acc[cb], 0, 0, 0);
            acc[cb] = __builtin_amdgcn_mfma_f32_16x16x32_bf16(a_lo, b_hi, acc[cb], 0, 0, 0);
            acc[cb] = __builtin_amdgcn_mfma_f32_16x16x32_bf16(a_hi, b_lo, acc[cb], 0, 0, 0);
        }
    }

    // --- scatter: C/D layout col = cb*16 + m, row = wave*16 + quad*4 + reg ---
    const int rbase = wave * 16 + quad * 4;
#pragma unroll
    for (int reg = 0; reg < 4; ++reg) {
        int row = rbase + reg;
        if (row < valid) {
            long om = (long)sorted_om[pairbase + row];
            float* dst = out + om * Cc + m;
#pragma unroll
            for (int cb = 0; cb < 8; ++cb)
                unsafeAtomicAdd(dst + cb * 16, acc[cb][reg]);
        }
    }
}

// ---------------------------------------------------------------------------
// Kernel 7: per-channel sum and sum-of-squares over 400000 rows
// ---------------------------------------------------------------------------
__global__ __launch_bounds__(256) void stats_kernel(const float4* __restrict__ out4,
                                                    float* __restrict__ stats) {
    const int t  = threadIdx.x;
    const int tx = t & 31;
    const int ty = t >> 5;

    float4 s = make_float4(0.f, 0.f, 0.f, 0.f);
    float4 q = make_float4(0.f, 0.f, 0.f, 0.f);
    int row0 = blockIdx.x * 400 + ty;
    for (int j = 0; j < 50; ++j) {
        float4 v = out4[(row0 + j * 8) * 32 + tx];
        s.x += v.x; s.y += v.y; s.z += v.z; s.w += v.w;
        q.x += v.x * v.x; q.y += v.y * v.y; q.z += v.z * v.z; q.w += v.w * v.w;
    }

    __shared__ float4 redS[256];
    __shared__ float4 redQ[256];
    redS[t] = s; redQ[t] = q;
    __syncthreads();
    if (ty == 0) {
#pragma unroll
        for (int jj = 1; jj < 8; ++jj) {
            float4 o = redS[jj * 32 + tx];
            s.x += o.x; s.y += o.y; s.z += o.z; s.w += o.w;
            float4 oq = redQ[jj * 32 + tx];
            q.x += oq.x; q.y += oq.y; q.z += oq.z; q.w += oq.w;
        }
        unsafeAtomicAdd(&stats[tx * 4 + 0], s.x);
        unsafeAtomicAdd(&stats[tx * 4 + 1], s.y);
        unsafeAtomicAdd(&stats[tx * 4 + 2], s.z);
        unsafeAtomicAdd(&stats[tx * 4 + 3], s.w);
        unsafeAtomicAdd(&stats[Cc + tx * 4 + 0], q.x);
        unsafeAtomicAdd(&stats[Cc + tx * 4 + 1], q.y);
        unsafeAtomicAdd(&stats[Cc + tx * 4 + 2], q.z);
        unsafeAtomicAdd(&stats[Cc + tx * 4 + 3], q.w);
    }
}

// ---------------------------------------------------------------------------
// Kernel 8: finalize BN scale/shift per channel
// ---------------------------------------------------------------------------
__global__ void finalize_kernel(const float* __restrict__ gamma,
                                const float* __restrict__ beta,
                                float* __restrict__ stats) {
    int c = threadIdx.x;
    float inv_n = 1.0f / (float)NOUTc;
    float mean = stats[c] * inv_n;
    float var  = stats[Cc + c] * inv_n - mean * mean;
    float scale = gamma[c] * rsqrtf(var + EPSc);
    stats[2 * Cc + c] = scale;
    stats[3 * Cc + c] = beta[c] - mean * scale;
}

// ---------------------------------------------------------------------------
// Kernel 9: in-place normalize  y = out*scale[c] + shift[c]
// ---------------------------------------------------------------------------
__global__ __launch_bounds__(256) void norm_kernel(float4* __restrict__ out4,
                                                   const float* __restrict__ stats) {
    const float4* stats4 = (const float4*)stats;
    int idx0 = blockIdx.x * blockDim.x + threadIdx.x;
    int c4 = idx0 & 31;
    float4 sc = stats4[64 + c4];
    float4 sh = stats4[96 + c4];
    const int n4 = NOUTc * (Cc / 4);
    const int stride = gridDim.x * blockDim.x;
    for (int i = idx0; i < n4; i += stride) {
        float4 v = out4[i];
        v.x = v.x * sc.x + sh.x;
        v.y = v.y * sc.y + sh.y;
        v.z = v.z * sc.z + sh.z;
        v.w = v.w * sc.w + sh.w;
        out4[i] = v;
    }
}

// ---------------------------------------------------------------------------
extern "C" void kernel_launch(void* const* d_in, const int* in_sizes, int n_in,
                              void* d_out, int out_size, void* d_ws, size_t ws_size,
                              hipStream_t stream) {
    const float* feats    = (const float*)d_in[0];
    const float* W        = (const float*)d_in[1];
    const float* gamma    = (const float*)d_in[2];
    const float* beta     = (const float*)d_in[3];
    const int*   in_maps  = (const int*)d_in[4];
    const int*   out_maps = (const int*)d_in[5];
    float* out = (float*)d_out;

    char* ws = (char*)d_ws;
    float*    stats     = (float*)(ws + WS_STATS);
    unsigned* counts    = (unsigned*)(ws + WS_COUNTS);
    int*      sorted_im = (int*)(ws + WS_SIM);
    int*      sorted_om = (int*)(ws + WS_SOM);
    short8*   wfh       = (short8*)(ws + WS_WFH);
    short8*   wfl       = (short8*)(ws + WS_WFL);

    zero_kernel<<<4096, 256, 0, stream>>>((float4*)out, stats, counts);
    wprep_kernel<<<216, 256, 0, stream>>>(W, wfh, wfl);
    hist_kernel<<<K3c * BPK, 256, 0, stream>>>(out_maps, counts);
    scan_kernel<<<1, 1024, 0, stream>>>(counts);
    build_kernel<<<K3c * BPK, 256, 0, stream>>>(in_maps, out_maps, counts,
                                                sorted_im, sorted_om);
    gemm_scatter_kernel<<<K3c * CPK, 256, 0, stream>>>(feats, wfh, wfl,
                                                       sorted_im, sorted_om, out);
    stats_kernel<<<1000, 256, 0, stream>>>((const float4*)out, stats);
    finalize_kernel<<<1, 128, 0, stream>>>(gamma, beta, stats);
    norm_kernel<<<4096, 256, 0, stream>>>((float4*)out, stats);
}